// Round 10
// baseline (21.613 us; speedup 1.0000x reference)
//
#include <hip/hip_runtime.h>
#include <hip/hip_bf16.h>

// ---- problem constants ----
#define B_TOK   128
#define E_TOP   4
#define NEXP    32
#define KDIM    512
#define CDIM    1024
#define PAIRS   (B_TOK * E_TOP)   // 512
#define HALF_C  (CDIM / 2)        // 512

#define ALPHA   1.702f
#define LIMIT   7.0f

typedef __attribute__((ext_vector_type(8))) short short8;   // bf16x8 frag
typedef __attribute__((ext_vector_type(4))) float f32x4;

__device__ __forceinline__ unsigned pk2(float a, float b) {
    union { __hip_bfloat16 h; unsigned short u; } ca, cb;
    ca.h = __float2bfloat16(a);
    cb.h = __float2bfloat16(b);
    return (unsigned)ca.u | ((unsigned)cb.u << 16);
}

__device__ __forceinline__ short8 cvt8(float4 lo, float4 hi) {
    union { unsigned u[4]; short8 s; } r;
    r.u[0] = pk2(lo.x, lo.y);
    r.u[1] = pk2(lo.z, lo.w);
    r.u[2] = pk2(hi.x, hi.y);
    r.u[3] = pk2(hi.z, hi.w);
    return r.s;
}

__device__ __forceinline__ float glu_act(float g, float l) {
    g = fminf(g, LIMIT);
    l = fminf(fmaxf(l, -LIMIT), LIMIT);
    const float sg = 1.0f / (1.0f + __expf(-ALPHA * g));
    return (g * sg) * (l + 1.0f);
}

#define LDF4(p, off) (*(const float4*)((p) + (off)))

// =====================================================================
// Single fused kernel. Block = (32-ch chunk, expert); 4 waves =
// 2 k-halves x 2 ch-subgroups; wave tile = 16 ch x 32 tok x K/2.
//
// KEY SCHEDULING IDEA: the block's entire W chunk (16 dwordx4/wave,
// 64 KB/block) is issued AT KERNEL ENTRY -- W addresses depend only on
// blockIdx, so the HBM stream runs under the whole prologue (bucket
// scan + x staging + barriers). Per-CU HBM duty cycle ~continuous.
//
//  1. issue W stream (held in 64 VGPRs, reused across token chunks)
//  2. inline bucket: scan idx[512] (L2-hot), LDS atomicAdd
//  3. stage x fp32 -> bf16 frag-linear LDS (skip upper half if nT<=16)
//  4. 8 MFMA steps x 1-2 MFMAs; 2-way k-combine; lane-local GLU store
// =====================================================================
__global__ __launch_bounds__(256, 4) void moe_mlp1_kernel(
    const float* __restrict__ x,      // [128, 512]
    const int* __restrict__ idx,      // [128, 4]
    const float* __restrict__ w,      // [32, 1024, 512]
    const float* __restrict__ bias,   // [32, 1024]
    float* __restrict__ out)          // [512, 512] fp32
{
    __shared__ char  xbl[32 * 1024];       // 32 frags x 1 KB
    __shared__ float red[2][64][8];        // 4 KB k-combine
    __shared__ unsigned short list[PAIRS]; // 1 KB
    __shared__ int cnt;

    const int e     = blockIdx.y;
    const int cBase = blockIdx.x * 32;
    const int tid   = threadIdx.x;
    const int wv    = tid >> 6;
    const int lane  = tid & 63;
    const int kh    = wv >> 1;         // k-half
    const int cs    = wv & 1;          // channel sub-group
    const int kg    = lane >> 4;       // k-group within MFMA step
    const int c16   = lane & 15;
    const int tA    = lane & 15;

    // ---- 1. W stream: ALL 16 dwordx4 issued NOW, before anything ----
    const float* wp = w + ((size_t)e * CDIM + cBase + cs * 16 + c16) * KDIM
                        + kh * 256 + kg * 8;
    float4 w0[8], w1[8];
    #pragma unroll
    for (int p = 0; p < 8; ++p) {
        w0[p] = LDF4(wp, p * 32);
        w1[p] = LDF4(wp, p * 32 + 4);
    }

    // ---- 2. inline bucket (runs under the W stream) ----
    if (tid == 0) cnt = 0;
    __syncthreads();
    #pragma unroll
    for (int r = 0; r < 2; ++r) {
        const int p = tid + r * 256;
        if (idx[p] == e) {
            const int pos = atomicAdd(&cnt, 1);
            list[pos] = (unsigned short)p;
        }
    }
    __syncthreads();
    const int T = cnt;

    const float4 bv = *(const float4*)(bias + (size_t)e * CDIM + cBase
                                       + cs * 16 + kg * 4);
    const int cb = cBase + cs * 16 + kg * 4;   // epilogue channels cb..cb+3

    for (int tb = 0; tb < T; tb += 32) {
        if (tb) __syncthreads();               // xbl/red reuse guard
        const int nT = min(32, T - tb);
        const bool h2 = nT > 16;               // block-uniform

        // ---- 3. stage x chunk: fp32 -> bf16, frag-linear LDS ----
        // unit u: token t = u&31, segment s = u>>5 (32 k's); frag
        // f = s*2 + (t>>4), lane slot (t&15)*16 + kg*256.
        #pragma unroll
        for (int r = 0; r < 2; ++r) {
            const int u = tid + r * 256;
            const int t = u & 31;
            const int s = u >> 5;
            if (t < nT) {
                const int pr = (int)list[tb + t];
                const float* xr = x + (size_t)(pr >> 2) * KDIM + s * 32;
                const float4 f0 = LDF4(xr, 0),  f1 = LDF4(xr, 4);
                const float4 f2 = LDF4(xr, 8),  f3 = LDF4(xr, 12);
                const float4 f4 = LDF4(xr, 16), f5 = LDF4(xr, 20);
                const float4 f6 = LDF4(xr, 24), f7 = LDF4(xr, 28);
                char* db = &xbl[(s * 2 + (t >> 4)) * 1024 + (t & 15) * 16];
                *(short8*)(db + 0 * 256) = cvt8(f0, f1);
                *(short8*)(db + 1 * 256) = cvt8(f2, f3);
                *(short8*)(db + 2 * 256) = cvt8(f4, f5);
                *(short8*)(db + 3 * 256) = cvt8(f6, f7);
            }
        }

        const int pr0 = (tA < nT)      ? (int)list[tb + tA]      : -1;
        const int pr1 = (tA + 16 < nT) ? (int)list[tb + tA + 16] : -1;

        __syncthreads();   // frags ready (W already long in flight / landed)

        // ---- 4. MFMA loop: W already in VGPRs ----
        f32x4 acc0 = {0.f, 0.f, 0.f, 0.f};
        f32x4 acc1 = {0.f, 0.f, 0.f, 0.f};
        const char* xb = &xbl[kh * 16384 + lane * 16];

        if (h2) {
            #pragma unroll
            for (int s = 0; s < 8; ++s) {
                const short8 a  = cvt8(w0[s], w1[s]);
                const short8 b0 = *(const short8*)(xb + s * 2048);
                const short8 b1 = *(const short8*)(xb + s * 2048 + 1024);
                acc0 = __builtin_amdgcn_mfma_f32_16x16x32_bf16(a, b0, acc0, 0, 0, 0);
                acc1 = __builtin_amdgcn_mfma_f32_16x16x32_bf16(a, b1, acc1, 0, 0, 0);
            }
        } else {
            #pragma unroll
            for (int s = 0; s < 8; ++s) {
                const short8 a  = cvt8(w0[s], w1[s]);
                const short8 b0 = *(const short8*)(xb + s * 2048);
                acc0 = __builtin_amdgcn_mfma_f32_16x16x32_bf16(a, b0, acc0, 0, 0, 0);
            }
        }

        // ---- 2-way k-combine + lane-local GLU epilogue ----
        if (kh == 1) {
            #pragma unroll
            for (int i = 0; i < 4; ++i) {
                red[cs][lane][i]     = acc0[i];
                red[cs][lane][4 + i] = acc1[i];
            }
        }
        __syncthreads();
        if (kh == 0) {
            #pragma unroll
            for (int i = 0; i < 4; ++i) {
                acc0[i] += red[cs][lane][i];
                acc1[i] += red[cs][lane][4 + i];
            }
            if (pr0 >= 0) {
                float2 o;
                o.x = glu_act(acc0[0] + bv.x, acc0[1] + bv.y);
                o.y = glu_act(acc0[2] + bv.z, acc0[3] + bv.w);
                *(float2*)&out[(size_t)pr0 * HALF_C + (cb >> 1)] = o;
            }
            if (pr1 >= 0) {
                float2 o;
                o.x = glu_act(acc1[0] + bv.x, acc1[1] + bv.y);
                o.y = glu_act(acc1[2] + bv.z, acc1[3] + bv.w);
                *(float2*)&out[(size_t)pr1 * HALF_C + (cb >> 1)] = o;
            }
        }
    }
}

extern "C" void kernel_launch(void* const* d_in, const int* in_sizes, int n_in,
                              void* d_out, int out_size, void* d_ws, size_t ws_size,
                              hipStream_t stream) {
    const float* x    = (const float*)d_in[0];
    const int*   idx  = (const int*)d_in[1];
    const float* w    = (const float*)d_in[2];
    const float* bias = (const float*)d_in[3];
    float* out = (float*)d_out;

    dim3 grid(CDIM / 32, NEXP);   // (32, 32) = 1024 blocks = 4/CU
    moe_mlp1_kernel<<<grid, 256, 0, stream>>>(x, idx, w, bias, out);
}